// Round 12
// baseline (949.567 us; speedup 1.0000x reference)
//
#include <hip/hip_runtime.h>
#include <hip/hip_bf16.h>

// Problem constants
#define TT 512
#define BB 256
#define II 120
#define HH 128
#define GG 512   // 4*H
#define D1 512
#define NOUT 7
#define TB (TT*BB)  // 131072

typedef _Float16 f16x2 __attribute__((ext_vector_type(2)));
typedef _Float16 f16x4 __attribute__((ext_vector_type(4)));
typedef _Float16 f16x8 __attribute__((ext_vector_type(8)));
typedef float    f32x4 __attribute__((ext_vector_type(4)));

// ---------- static device scratch ----------
__device__ unsigned short g_xg[(size_t)TB * GG];   // [T*B, 512] bf16
__device__ _Float16       g_h0[(size_t)TB * HH];   // [T*B, 128] f16
__device__ float          g_pooled[BB * HH];

// ---------- helpers ----------
__device__ inline float bf2f(unsigned short u) {
    return __uint_as_float(((unsigned)u) << 16);
}
__device__ inline unsigned short f2bf(float f) {
    unsigned u = __float_as_uint(f);
    return (unsigned short)((u + 0x7fffu + ((u >> 16) & 1u)) >> 16);
}
__device__ inline float fdot2(f16x2 a, f16x2 b, float c) {
#if __has_builtin(__builtin_amdgcn_fdot2)
    return __builtin_amdgcn_fdot2(a, b, c, false);
#else
    return c + (float)a[0] * (float)b[0] + (float)a[1] * (float)b[1];
#endif
}
// DPP pair swap within quads: [1,0,3,2] — lanes 2u <-> 2u+1
__device__ inline float dpp_xor1(float v) {
#if __has_builtin(__builtin_amdgcn_mov_dpp)
    return __int_as_float(
        __builtin_amdgcn_mov_dpp(__float_as_int(v), 0xB1, 0xf, 0xf, true));
#else
    return __shfl_xor(v, 1, 4);
#endif
}

// ---------- MFMA GEMM: xg[n,g] = sum_k A[n,k]*W[g,k] + bia[g]+bib[g] ----------
// f16 MFMA 16x16x32. Block: 128(M)x128(N), 512 threads = 8 waves (2x4 of 64x32).
template <int LAYER>
__global__ __launch_bounds__(512) void gemm_mfma_kernel(
    const float* __restrict__ A0,     // [TB, II] (LAYER 0 only)
    const float* __restrict__ W,      // [512, F] f32
    const float* __restrict__ bia,
    const float* __restrict__ bib)
{
    const int F  = (LAYER == 0) ? II : HH;
    const int m0 = blockIdx.x * 128;
    const int n0 = blockIdx.y * 128;
    const int t    = threadIdx.x;
    const int lane = t & 63;
    const int wv   = t >> 6;         // 0..7
    const int wm   = wv >> 2;        // 0..1 -> rows wm*64
    const int wn   = wv & 3;         // 0..3 -> cols wn*32
    const int l15  = lane & 15;
    const int lhi  = lane >> 4;      // 0..3

    __shared__ _Float16 As[128][40];
    __shared__ _Float16 Bs[128][40];

    f32x4 acc[4][2];
#pragma unroll
    for (int mi = 0; mi < 4; ++mi)
#pragma unroll
        for (int ni = 0; ni < 2; ++ni)
            acc[mi][ni] = f32x4{0.f, 0.f, 0.f, 0.f};

    const int srow = t >> 2;   // staging row 0..127
    const int q    = t & 3;    // k-slot: covers k0+q*8 .. +7

#pragma unroll 1
    for (int kc = 0; kc < 4; ++kc) {
        const int k0 = kc * 32;
        if (LAYER == 0) {
#pragma unroll
            for (int h = 0; h < 2; ++h) {
                int k = k0 + q * 8 + h * 4;
                float4 v = make_float4(0.f, 0.f, 0.f, 0.f);
                if (k + 4 <= F) v = *(const float4*)&A0[(size_t)(m0 + srow) * II + k];
                f16x4 hv = {(_Float16)v.x, (_Float16)v.y, (_Float16)v.z, (_Float16)v.w};
                *(f16x4*)&As[srow][q * 8 + h * 4] = hv;
            }
        } else {
            int k = k0 + q * 8;   // F=128: always valid
            f16x8 v = *(const f16x8*)&g_h0[(size_t)(m0 + srow) * HH + k];
            *(f16x8*)&As[srow][q * 8] = v;
        }
#pragma unroll
        for (int h = 0; h < 2; ++h) {
            int k = k0 + q * 8 + h * 4;
            float4 v = make_float4(0.f, 0.f, 0.f, 0.f);
            if (k + 4 <= F) v = *(const float4*)&W[(size_t)(n0 + srow) * F + k];
            f16x4 hv = {(_Float16)v.x, (_Float16)v.y, (_Float16)v.z, (_Float16)v.w};
            *(f16x4*)&Bs[srow][q * 8 + h * 4] = hv;
        }
        __syncthreads();

        f16x8 af[4], bf[2];
#pragma unroll
        for (int mi = 0; mi < 4; ++mi)
            af[mi] = *(const f16x8*)&As[wm * 64 + mi * 16 + l15][lhi * 8];
#pragma unroll
        for (int ni = 0; ni < 2; ++ni)
            bf[ni] = *(const f16x8*)&Bs[wn * 32 + ni * 16 + l15][lhi * 8];
#pragma unroll
        for (int mi = 0; mi < 4; ++mi)
#pragma unroll
            for (int ni = 0; ni < 2; ++ni)
                acc[mi][ni] = __builtin_amdgcn_mfma_f32_16x16x32_f16(
                    af[mi], bf[ni], acc[mi][ni], 0, 0, 0);
        __syncthreads();
    }

#pragma unroll
    for (int ni = 0; ni < 2; ++ni) {
        const int col = n0 + wn * 32 + ni * 16 + l15;
        const float bc = bia[col] + bib[col];
#pragma unroll
        for (int mi = 0; mi < 4; ++mi) {
#pragma unroll
            for (int j = 0; j < 4; ++j) {
                const int grow = m0 + wm * 64 + mi * 16 + lhi * 4 + j;
                g_xg[(size_t)grow * GG + col] = f2bf(acc[mi][ni][j] + bc);
            }
        }
    }
}

// ---------- LSTM recurrence: 256 threads, 1 wave/SIMD, 2 batch elems/block ----------
// r11 measured: step = 1280 cyc, of which only ~300 is issue; the rest is the
// serial per-step tail (LDS latency + reduce->exp->swap->cell chain + barrier
// + drain) during which the lone wave's VALU idles (VALUBusy 46%).
// Fix: interleave TWO batch elements per block. Weights are batch-shared
// (zero extra registers); the two elements' serial chains are independent,
// so element B's dot issue and element A's chain overlap. ~2x throughput.
// Thread t -> (u = t>>1, q = t&1); q=0 owns rows {u(i), 128+u(f)},
// q=1 owns {256+u(g), 384+u(o)}; full K=128; one DPP pair swap exchanges.
template <int LAYER>
__global__ __launch_bounds__(256) void lstm_kernel(
    const float* __restrict__ Whh,   // [512,128]
    const int* __restrict__ lens)
{
    const int b0 = blockIdx.x * 2;
    const int b1 = b0 + 1;
    const int t = threadIdx.x;
    const int u = t >> 1;        // unit 0..127
    const int q = t & 1;         // row-pair selector
    const int r0 = q * 256 + u;  // i (q=0) or g (q=1)
    const int r1 = r0 + 128;     // f (q=0) or o (q=1)

    __shared__ __align__(16) _Float16 h_lds[2][2][HH];   // [elem][buf][unit]

    f16x2 w0[64], w1[64];
#pragma unroll
    for (int k4 = 0; k4 < 32; ++k4) {
        float4 v = *(const float4*)&Whh[(size_t)r0 * HH + k4 * 4];
        w0[k4 * 2 + 0] = f16x2{(_Float16)v.x, (_Float16)v.y};
        w0[k4 * 2 + 1] = f16x2{(_Float16)v.z, (_Float16)v.w};
        float4 v2 = *(const float4*)&Whh[(size_t)r1 * HH + k4 * 4];
        w1[k4 * 2 + 0] = f16x2{(_Float16)v2.x, (_Float16)v2.y};
        w1[k4 * 2 + 1] = f16x2{(_Float16)v2.z, (_Float16)v2.w};
    }
    if (t < HH) {
        h_lds[0][0][t] = (_Float16)0.f; h_lds[0][1][t] = (_Float16)0.f;
        h_lds[1][0][t] = (_Float16)0.f; h_lds[1][1][t] = (_Float16)0.f;
    }
    float cA = 0.f, cB = 0.f, poolA = 0.f, poolB = 0.f;
    const int lenA = lens[b0];
    const int lenB = lens[b1];
    __syncthreads();

    const unsigned short* xa = g_xg + (size_t)b0 * GG;
    const unsigned short* xb = g_xg + (size_t)b1 * GG;
    const size_t xstride = (size_t)BB * GG;
    float xA0 = bf2f(xa[r0]), xA1 = bf2f(xa[r1]);
    float xB0 = bf2f(xb[r0]), xB1 = bf2f(xb[r1]);

    // act0: q=0 -> sigm(x) ; q=1 -> tanh(x) = 2*sigm(2x)-1 (branchless)
    const float am = q ? 2.f : 1.f;
    const float as = q ? 2.f : 1.f;
    const float ao = q ? -1.f : 0.f;

    for (int step = 0; step < TT; ++step) {
        float nA0 = 0.f, nA1 = 0.f, nB0 = 0.f, nB1 = 0.f;
        if (step + 1 < TT) {
            const unsigned short* xna = xa + (size_t)(step + 1) * xstride;
            const unsigned short* xnb = xb + (size_t)(step + 1) * xstride;
            nA0 = bf2f(xna[r0]); nA1 = bf2f(xna[r1]);
            nB0 = bf2f(xnb[r0]); nB1 = bf2f(xnb[r1]);
        }
        const int rd = step & 1, wr = rd ^ 1;

        // ---- dots: elem A then elem B (16 independent 8-deep chains) ----
        float aA00 = 0.f, aA01 = 0.f, aA02 = 0.f, aA03 = 0.f;
        float aA10 = 0.f, aA11 = 0.f, aA12 = 0.f, aA13 = 0.f;
#pragma unroll
        for (int seg = 0; seg < 8; ++seg) {
            f16x8 hv = *(const f16x8*)&h_lds[0][rd][seg * 8];   // broadcast
            f16x2 hA = {hv[0], hv[1]}, hB = {hv[2], hv[3]};
            f16x2 hC = {hv[4], hv[5]}, hD = {hv[6], hv[7]};
            aA00 = fdot2(w0[seg * 4 + 0], hA, aA00);
            aA01 = fdot2(w0[seg * 4 + 1], hB, aA01);
            aA02 = fdot2(w0[seg * 4 + 2], hC, aA02);
            aA03 = fdot2(w0[seg * 4 + 3], hD, aA03);
            aA10 = fdot2(w1[seg * 4 + 0], hA, aA10);
            aA11 = fdot2(w1[seg * 4 + 1], hB, aA11);
            aA12 = fdot2(w1[seg * 4 + 2], hC, aA12);
            aA13 = fdot2(w1[seg * 4 + 3], hD, aA13);
        }
        float aB00 = 0.f, aB01 = 0.f, aB02 = 0.f, aB03 = 0.f;
        float aB10 = 0.f, aB11 = 0.f, aB12 = 0.f, aB13 = 0.f;
#pragma unroll
        for (int seg = 0; seg < 8; ++seg) {
            f16x8 hv = *(const f16x8*)&h_lds[1][rd][seg * 8];   // broadcast
            f16x2 hA = {hv[0], hv[1]}, hB = {hv[2], hv[3]};
            f16x2 hC = {hv[4], hv[5]}, hD = {hv[6], hv[7]};
            aB00 = fdot2(w0[seg * 4 + 0], hA, aB00);
            aB01 = fdot2(w0[seg * 4 + 1], hB, aB01);
            aB02 = fdot2(w0[seg * 4 + 2], hC, aB02);
            aB03 = fdot2(w0[seg * 4 + 3], hD, aB03);
            aB10 = fdot2(w1[seg * 4 + 0], hA, aB10);
            aB11 = fdot2(w1[seg * 4 + 1], hB, aB11);
            aB12 = fdot2(w1[seg * 4 + 2], hC, aB12);
            aB13 = fdot2(w1[seg * 4 + 3], hD, aB13);
        }

        // ---- update elem A ----
        const float aA0 = (aA00 + aA01) + (aA02 + aA03) + xA0;
        const float aA1 = (aA10 + aA11) + (aA12 + aA13) + xA1;
        const float sA0 = 1.f / (1.f + __expf(-(aA0 * am)));
        const float actA0 = sA0 * as + ao;
        const float actA1 = 1.f / (1.f + __expf(-aA1));
        const float pA0 = dpp_xor1(actA0);
        const float pA1 = dpp_xor1(actA1);
        const float iA = q ? pA0 : actA0;
        const float fA = q ? pA1 : actA1;
        const float gA = q ? actA0 : pA0;
        const float oA = q ? actA1 : pA1;
        cA = fA * cA + iA * gA;
        const float thA = 2.f / (1.f + __expf(-2.f * cA)) - 1.f;
        const float hvA = oA * thA;

        // ---- update elem B (independent chain, overlaps A's latency) ----
        const float aB0 = (aB00 + aB01) + (aB02 + aB03) + xB0;
        const float aB1 = (aB10 + aB11) + (aB12 + aB13) + xB1;
        const float sB0 = 1.f / (1.f + __expf(-(aB0 * am)));
        const float actB0 = sB0 * as + ao;
        const float actB1 = 1.f / (1.f + __expf(-aB1));
        const float pB0 = dpp_xor1(actB0);
        const float pB1 = dpp_xor1(actB1);
        const float iB = q ? pB0 : actB0;
        const float fB = q ? pB1 : actB1;
        const float gB = q ? actB0 : pB0;
        const float oB = q ? actB1 : pB1;
        cB = fB * cB + iB * gB;
        const float thB = 2.f / (1.f + __expf(-2.f * cB)) - 1.f;
        const float hvB = oB * thB;

        if (LAYER == 0) {
            if (q) {
                g_h0[((size_t)step * BB + b0) * HH + u] = (_Float16)hvA;
                g_h0[((size_t)step * BB + b1) * HH + u] = (_Float16)hvB;
            }
        } else {
            if (step < lenA) {
                const float ah = fabsf(hvA);
                poolA += ah * sqrtf(ah);   // |h|^1.5
            }
            if (step < lenB) {
                const float ah = fabsf(hvB);
                poolB += ah * sqrtf(ah);
            }
        }
        if (!q) {
            h_lds[0][wr][u] = (_Float16)hvA;
            h_lds[1][wr][u] = (_Float16)hvB;
        }
        __syncthreads();
        xA0 = nA0; xA1 = nA1; xB0 = nB0; xB1 = nB1;
    }

    if (LAYER == 1 && !q) {
        g_pooled[b0 * HH + u] = powf(poolA, 2.f / 3.f) * powf((float)lenA, -2.f / 3.f);
        g_pooled[b1 * HH + u] = powf(poolB, 2.f / 3.f) * powf((float)lenB, -2.f / 3.f);
    }
}

// ---------- MLP + softmax ----------
__global__ __launch_bounds__(512) void mlp_kernel(
    const float* __restrict__ W1, const float* __restrict__ b1,
    const float* __restrict__ W2, const float* __restrict__ b2,
    float* __restrict__ out)
{
    const int b = blockIdx.x;
    const int t = threadIdx.x;
    __shared__ __align__(16) float pl[HH];
    __shared__ float x1[D1];
    __shared__ float lg[NOUT];

    if (t < HH) pl[t] = g_pooled[b * HH + t];
    __syncthreads();

    float acc = b1[t];
#pragma unroll
    for (int k4 = 0; k4 < 32; ++k4) {
        float4 wv = *(const float4*)&W1[(size_t)t * HH + k4 * 4];
        float4 pv = *(const float4*)&pl[k4 * 4];
        acc += wv.x * pv.x + wv.y * pv.y + wv.z * pv.z + wv.w * pv.w;
    }
    x1[t] = fmaxf(acc, 0.f);
    __syncthreads();

    if (t < NOUT) {
        float a = b2[t];
        for (int d = 0; d < D1; ++d) a += x1[d] * W2[(size_t)t * D1 + d];
        lg[t] = a;
    }
    __syncthreads();
    if (t < NOUT) {
        float m = lg[0];
#pragma unroll
        for (int j = 1; j < NOUT; ++j) m = fmaxf(m, lg[j]);
        float s = 0.f;
#pragma unroll
        for (int j = 0; j < NOUT; ++j) s += __expf(lg[j] - m);
        out[b * NOUT + t] = __expf(lg[t] - m) / s;
    }
}

// ---------- launch ----------
extern "C" void kernel_launch(void* const* d_in, const int* in_sizes, int n_in,
                              void* d_out, int out_size, void* d_ws, size_t ws_size,
                              hipStream_t stream)
{
    const float* x      = (const float*)d_in[0];
    const int*   lens   = (const int*)d_in[1];
    const float* W_ih0  = (const float*)d_in[2];
    const float* W_hh0  = (const float*)d_in[3];
    const float* b_ih0  = (const float*)d_in[4];
    const float* b_hh0  = (const float*)d_in[5];
    const float* W_ih1  = (const float*)d_in[6];
    const float* W_hh1  = (const float*)d_in[7];
    const float* b_ih1  = (const float*)d_in[8];
    const float* b_hh1  = (const float*)d_in[9];
    const float* W1     = (const float*)d_in[10];
    const float* b1     = (const float*)d_in[11];
    const float* W2     = (const float*)d_in[12];
    const float* b2     = (const float*)d_in[13];
    float* out = (float*)d_out;

    dim3 gg(TB / 128, GG / 128);   // (1024, 4)
    gemm_mfma_kernel<0><<<gg, 512, 0, stream>>>(x, W_ih0, b_ih0, b_hh0);
    lstm_kernel<0><<<BB / 2, 256, 0, stream>>>(W_hh0, lens);
    gemm_mfma_kernel<1><<<gg, 512, 0, stream>>>(x, W_ih1, b_ih1, b_hh1);
    lstm_kernel<1><<<BB / 2, 256, 0, stream>>>(W_hh1, lens);
    mlp_kernel<<<BB, 512, 0, stream>>>(W1, b1, W2, b2, out);
}

// Round 13
// 687.770 us; speedup vs baseline: 1.3806x; 1.3806x over previous
//
#include <hip/hip_runtime.h>
#include <hip/hip_bf16.h>

// Problem constants
#define TT 512
#define BB 256
#define II 120
#define HH 128
#define GG 512   // 4*H
#define D1 512
#define NOUT 7
#define TB (TT*BB)  // 131072

typedef _Float16 f16x2 __attribute__((ext_vector_type(2)));
typedef _Float16 f16x4 __attribute__((ext_vector_type(4)));
typedef _Float16 f16x8 __attribute__((ext_vector_type(8)));
typedef float    f32x4 __attribute__((ext_vector_type(4)));

// ---------- static device scratch ----------
__device__ unsigned short g_xg[(size_t)TB * GG];   // [T*B, 512] bf16
__device__ _Float16       g_h0[(size_t)TB * HH];   // [T*B, 128] f16
__device__ float          g_pooled[BB * HH];

// ---------- helpers ----------
__device__ inline float bf2f(unsigned short u) {
    return __uint_as_float(((unsigned)u) << 16);
}
__device__ inline unsigned short f2bf(float f) {
    unsigned u = __float_as_uint(f);
    return (unsigned short)((u + 0x7fffu + ((u >> 16) & 1u)) >> 16);
}
__device__ inline float fdot2(f16x2 a, f16x2 b, float c) {
#if __has_builtin(__builtin_amdgcn_fdot2)
    return __builtin_amdgcn_fdot2(a, b, c, false);
#else
    return c + (float)a[0] * (float)b[0] + (float)a[1] * (float)b[1];
#endif
}
__device__ inline f16x2 asf16x2(float f) { return __builtin_bit_cast(f16x2, f); }
// DPP pair swap within quads: [1,0,3,2] — lanes 2u <-> 2u+1
__device__ inline float dpp_xor1(float v) {
#if __has_builtin(__builtin_amdgcn_mov_dpp)
    return __int_as_float(
        __builtin_amdgcn_mov_dpp(__float_as_int(v), 0xB1, 0xf, 0xf, true));
#else
    return __shfl_xor(v, 1, 4);
#endif
}

// ---------- MFMA GEMM: xg[n,g] = sum_k A[n,k]*W[g,k] + bia[g]+bib[g] ----------
// f16 MFMA 16x16x32. Block: 128(M)x128(N), 512 threads = 8 waves (2x4 of 64x32).
template <int LAYER>
__global__ __launch_bounds__(512) void gemm_mfma_kernel(
    const float* __restrict__ A0,     // [TB, II] (LAYER 0 only)
    const float* __restrict__ W,      // [512, F] f32
    const float* __restrict__ bia,
    const float* __restrict__ bib)
{
    const int F  = (LAYER == 0) ? II : HH;
    const int m0 = blockIdx.x * 128;
    const int n0 = blockIdx.y * 128;
    const int t    = threadIdx.x;
    const int lane = t & 63;
    const int wv   = t >> 6;         // 0..7
    const int wm   = wv >> 2;        // 0..1 -> rows wm*64
    const int wn   = wv & 3;         // 0..3 -> cols wn*32
    const int l15  = lane & 15;
    const int lhi  = lane >> 4;      // 0..3

    __shared__ _Float16 As[128][40];
    __shared__ _Float16 Bs[128][40];

    f32x4 acc[4][2];
#pragma unroll
    for (int mi = 0; mi < 4; ++mi)
#pragma unroll
        for (int ni = 0; ni < 2; ++ni)
            acc[mi][ni] = f32x4{0.f, 0.f, 0.f, 0.f};

    const int srow = t >> 2;   // staging row 0..127
    const int q    = t & 3;    // k-slot: covers k0+q*8 .. +7

#pragma unroll 1
    for (int kc = 0; kc < 4; ++kc) {
        const int k0 = kc * 32;
        if (LAYER == 0) {
#pragma unroll
            for (int h = 0; h < 2; ++h) {
                int k = k0 + q * 8 + h * 4;
                float4 v = make_float4(0.f, 0.f, 0.f, 0.f);
                if (k + 4 <= F) v = *(const float4*)&A0[(size_t)(m0 + srow) * II + k];
                f16x4 hv = {(_Float16)v.x, (_Float16)v.y, (_Float16)v.z, (_Float16)v.w};
                *(f16x4*)&As[srow][q * 8 + h * 4] = hv;
            }
        } else {
            int k = k0 + q * 8;   // F=128: always valid
            f16x8 v = *(const f16x8*)&g_h0[(size_t)(m0 + srow) * HH + k];
            *(f16x8*)&As[srow][q * 8] = v;
        }
#pragma unroll
        for (int h = 0; h < 2; ++h) {
            int k = k0 + q * 8 + h * 4;
            float4 v = make_float4(0.f, 0.f, 0.f, 0.f);
            if (k + 4 <= F) v = *(const float4*)&W[(size_t)(n0 + srow) * F + k];
            f16x4 hv = {(_Float16)v.x, (_Float16)v.y, (_Float16)v.z, (_Float16)v.w};
            *(f16x4*)&Bs[srow][q * 8 + h * 4] = hv;
        }
        __syncthreads();

        f16x8 af[4], bf[2];
#pragma unroll
        for (int mi = 0; mi < 4; ++mi)
            af[mi] = *(const f16x8*)&As[wm * 64 + mi * 16 + l15][lhi * 8];
#pragma unroll
        for (int ni = 0; ni < 2; ++ni)
            bf[ni] = *(const f16x8*)&Bs[wn * 32 + ni * 16 + l15][lhi * 8];
#pragma unroll
        for (int mi = 0; mi < 4; ++mi)
#pragma unroll
            for (int ni = 0; ni < 2; ++ni)
                acc[mi][ni] = __builtin_amdgcn_mfma_f32_16x16x32_f16(
                    af[mi], bf[ni], acc[mi][ni], 0, 0, 0);
        __syncthreads();
    }

#pragma unroll
    for (int ni = 0; ni < 2; ++ni) {
        const int col = n0 + wn * 32 + ni * 16 + l15;
        const float bc = bia[col] + bib[col];
#pragma unroll
        for (int mi = 0; mi < 4; ++mi) {
#pragma unroll
            for (int j = 0; j < 4; ++j) {
                const int grow = m0 + wm * 64 + mi * 16 + lhi * 4 + j;
                g_xg[(size_t)grow * GG + col] = f2bf(acc[mi][ni][j] + bc);
            }
        }
    }
}

// ---------- LSTM recurrence: 256 threads, 1 wave/SIMD, PINNED weights ----------
// r11 ran this structure at 273us but VGPR_Count=72 revealed the compiler
// sank ~half the weight loads into the step loop (L2 re-stream ~51 B/cyc/CU
// ~= the per-CU L2 port ceiling -> the kernel was L2-bound, not VALU-bound).
// Fix: pin all 128 packed weight words in VGPRs via opaque asm ("+v") so the
// loads CANNOT be rematerialized. Cap at 256 threads = 256 VGPR; need ~190.
// Thread t -> (u = t>>1, q = t&1); q=0 owns rows {u(i), 128+u(f)},
// q=1 owns {256+u(g), 384+u(o)}; full K=128; one DPP pair swap exchanges.
template <int LAYER>
__global__ __launch_bounds__(256) void lstm_kernel(
    const float* __restrict__ Whh,   // [512,128]
    const int* __restrict__ lens)
{
    const int b = blockIdx.x;
    const int t = threadIdx.x;
    const int u = t >> 1;        // unit 0..127
    const int q = t & 1;         // row-pair selector
    const int r0 = q * 256 + u;  // i (q=0) or g (q=1)
    const int r1 = r0 + 128;     // f (q=0) or o (q=1)

    __shared__ __align__(16) _Float16 h_lds[2][HH];

    float w0r[64], w1r[64];      // f16x2 bit-packed in float
#pragma unroll
    for (int k4 = 0; k4 < 32; ++k4) {
        float4 v = *(const float4*)&Whh[(size_t)r0 * HH + k4 * 4];
        w0r[k4 * 2 + 0] = __builtin_bit_cast(float, f16x2{(_Float16)v.x, (_Float16)v.y});
        w0r[k4 * 2 + 1] = __builtin_bit_cast(float, f16x2{(_Float16)v.z, (_Float16)v.w});
        float4 v2 = *(const float4*)&Whh[(size_t)r1 * HH + k4 * 4];
        w1r[k4 * 2 + 0] = __builtin_bit_cast(float, f16x2{(_Float16)v2.x, (_Float16)v2.y});
        w1r[k4 * 2 + 1] = __builtin_bit_cast(float, f16x2{(_Float16)v2.z, (_Float16)v2.w});
    }
    // PIN: opaque no-op asm -> values can't be re-loaded from global; they
    // must live in VGPRs (or visibly spill to scratch -> WRITE_SIZE).
#pragma unroll
    for (int k = 0; k < 64; ++k) {
        asm volatile("" : "+v"(w0r[k]));
        asm volatile("" : "+v"(w1r[k]));
    }

    if (t < HH) {
        h_lds[0][t] = (_Float16)0.f;
        h_lds[1][t] = (_Float16)0.f;
    }
    float c = 0.f, pool = 0.f;
    const int len = lens[b];
    __syncthreads();

    const unsigned short* xb = g_xg + (size_t)b * GG;
    const size_t xstride = (size_t)BB * GG;
    float x0 = bf2f(xb[r0]);
    float x1 = bf2f(xb[r1]);

    // act0: q=0 -> sigm(x) ; q=1 -> tanh(x) = 2*sigm(2x)-1 (branchless)
    const float am = q ? 2.f : 1.f;    // input scale
    const float as = q ? 2.f : 1.f;    // output scale
    const float ao = q ? -1.f : 0.f;   // output offset

    for (int step = 0; step < TT; ++step) {
        float nx0 = 0.f, nx1 = 0.f;
        if (step + 1 < TT) {
            const unsigned short* xn = xb + (size_t)(step + 1) * xstride;
            nx0 = bf2f(xn[r0]);
            nx1 = bf2f(xn[r1]);
        }
        const int rd = step & 1, wr = rd ^ 1;

        // two full-K dots, 8 independent 8-deep chains
        float a00 = 0.f, a01 = 0.f, a02 = 0.f, a03 = 0.f;
        float a10 = 0.f, a11 = 0.f, a12 = 0.f, a13 = 0.f;
#pragma unroll
        for (int seg = 0; seg < 8; ++seg) {
            f16x8 hv = *(const f16x8*)&h_lds[rd][seg * 8];   // broadcast read
            f16x2 hA = {hv[0], hv[1]}, hB = {hv[2], hv[3]};
            f16x2 hC = {hv[4], hv[5]}, hD = {hv[6], hv[7]};
            a00 = fdot2(asf16x2(w0r[seg * 4 + 0]), hA, a00);
            a01 = fdot2(asf16x2(w0r[seg * 4 + 1]), hB, a01);
            a02 = fdot2(asf16x2(w0r[seg * 4 + 2]), hC, a02);
            a03 = fdot2(asf16x2(w0r[seg * 4 + 3]), hD, a03);
            a10 = fdot2(asf16x2(w1r[seg * 4 + 0]), hA, a10);
            a11 = fdot2(asf16x2(w1r[seg * 4 + 1]), hB, a11);
            a12 = fdot2(asf16x2(w1r[seg * 4 + 2]), hC, a12);
            a13 = fdot2(asf16x2(w1r[seg * 4 + 3]), hD, a13);
        }
        const float a0 = (a00 + a01) + (a02 + a03) + x0;
        const float a1 = (a10 + a11) + (a12 + a13) + x1;

        // activations (branchless): act0 = sigm/tanh, act1 = sigm
        const float s0 = 1.f / (1.f + __expf(-(a0 * am)));
        const float act0 = s0 * as + ao;
        const float act1 = 1.f / (1.f + __expf(-a1));

        // pair exchange: (u,0) has i,f ; (u,1) has g,o
        const float p0 = dpp_xor1(act0);
        const float p1 = dpp_xor1(act1);
        const float i_ = q ? p0 : act0;
        const float f_ = q ? p1 : act1;
        const float g_ = q ? act0 : p0;
        const float o_ = q ? act1 : p1;

        c = f_ * c + i_ * g_;
        const float e2 = __expf(-2.f * c);
        const float th = 2.f / (1.f + e2) - 1.f;
        const float hv2 = o_ * th;

        if (LAYER == 0) {
            if (q) g_h0[((size_t)step * BB + b) * HH + u] = (_Float16)hv2;
        } else {
            if (step < len) {
                const float ah = fabsf(hv2);
                pool += ah * sqrtf(ah);   // |h|^1.5
            }
        }
        if (!q) h_lds[wr][u] = (_Float16)hv2;
        __syncthreads();
        x0 = nx0;
        x1 = nx1;
    }

    if (LAYER == 1 && !q) {
        const float s = powf(pool, 2.f / 3.f) * powf((float)len, -2.f / 3.f);
        g_pooled[b * HH + u] = s;
    }
}

// ---------- MLP + softmax ----------
__global__ __launch_bounds__(512) void mlp_kernel(
    const float* __restrict__ W1, const float* __restrict__ b1,
    const float* __restrict__ W2, const float* __restrict__ b2,
    float* __restrict__ out)
{
    const int b = blockIdx.x;
    const int t = threadIdx.x;
    __shared__ __align__(16) float pl[HH];
    __shared__ float x1[D1];
    __shared__ float lg[NOUT];

    if (t < HH) pl[t] = g_pooled[b * HH + t];
    __syncthreads();

    float acc = b1[t];
#pragma unroll
    for (int k4 = 0; k4 < 32; ++k4) {
        float4 wv = *(const float4*)&W1[(size_t)t * HH + k4 * 4];
        float4 pv = *(const float4*)&pl[k4 * 4];
        acc += wv.x * pv.x + wv.y * pv.y + wv.z * pv.z + wv.w * pv.w;
    }
    x1[t] = fmaxf(acc, 0.f);
    __syncthreads();

    if (t < NOUT) {
        float a = b2[t];
        for (int d = 0; d < D1; ++d) a += x1[d] * W2[(size_t)t * D1 + d];
        lg[t] = a;
    }
    __syncthreads();
    if (t < NOUT) {
        float m = lg[0];
#pragma unroll
        for (int j = 1; j < NOUT; ++j) m = fmaxf(m, lg[j]);
        float s = 0.f;
#pragma unroll
        for (int j = 0; j < NOUT; ++j) s += __expf(lg[j] - m);
        out[b * NOUT + t] = __expf(lg[t] - m) / s;
    }
}

// ---------- launch ----------
extern "C" void kernel_launch(void* const* d_in, const int* in_sizes, int n_in,
                              void* d_out, int out_size, void* d_ws, size_t ws_size,
                              hipStream_t stream)
{
    const float* x      = (const float*)d_in[0];
    const int*   lens   = (const int*)d_in[1];
    const float* W_ih0  = (const float*)d_in[2];
    const float* W_hh0  = (const float*)d_in[3];
    const float* b_ih0  = (const float*)d_in[4];
    const float* b_hh0  = (const float*)d_in[5];
    const float* W_ih1  = (const float*)d_in[6];
    const float* W_hh1  = (const float*)d_in[7];
    const float* b_ih1  = (const float*)d_in[8];
    const float* b_hh1  = (const float*)d_in[9];
    const float* W1     = (const float*)d_in[10];
    const float* b1     = (const float*)d_in[11];
    const float* W2     = (const float*)d_in[12];
    const float* b2     = (const float*)d_in[13];
    float* out = (float*)d_out;

    dim3 gg(TB / 128, GG / 128);   // (1024, 4)
    gemm_mfma_kernel<0><<<gg, 512, 0, stream>>>(x, W_ih0, b_ih0, b_hh0);
    lstm_kernel<0><<<BB, 256, 0, stream>>>(W_hh0, lens);
    gemm_mfma_kernel<1><<<gg, 512, 0, stream>>>(x, W_ih1, b_ih1, b_hh1);
    lstm_kernel<1><<<BB, 256, 0, stream>>>(W_hh1, lens);
    mlp_kernel<<<BB, 512, 0, stream>>>(W1, b1, W2, b2, out);
}